// Round 16
// baseline (214.721 us; speedup 1.0000x reference)
//
#include <hip/hip_runtime.h>

#define N_NODES 100000
#define N_EDGES 800000
#define IN_F 64
#define HID 128
#define OUT_F 64
#define BN_EPS 1e-5f
#define SCAN_NBLK ((N_NODES + 255) / 256)  // 391

typedef __attribute__((ext_vector_type(8))) short short8v;
typedef __attribute__((ext_vector_type(4))) float f32x4;

static __device__ __forceinline__ unsigned short f2bf(float f) {
  unsigned u = __float_as_uint(f);
  return (unsigned short)((u + 0x7FFFu + ((u >> 16) & 1u)) >> 16);
}
static __device__ __forceinline__ float bflo(unsigned u) {
  return __uint_as_float(u << 16);
}
static __device__ __forceinline__ float bfhi(unsigned u) {
  return __uint_as_float(u & 0xFFFF0000u);
}

// ---------------------------------------------------------------------------
// prep: xb = bf16(x); cursor = 0; wb1/wb2 = bf16 transposed [col][k] weights.
// wb1[col*128+k] = concatK [Ws1;Wn1][k][col];  wb2[col*128+k] = [Wn2|Ws2].
// ---------------------------------------------------------------------------
__global__ __launch_bounds__(256) void prep_kernel(
    const float* __restrict__ x, const float* __restrict__ Ws1,
    const float* __restrict__ Wn1, const float* __restrict__ Wn2,
    const float* __restrict__ Ws2, unsigned short* __restrict__ xb,
    unsigned short* __restrict__ wb1, unsigned short* __restrict__ wb2,
    int* __restrict__ cursor) {
  int t = blockIdx.x * 256 + threadIdx.x;
  if (t < N_NODES / 4) {  // 25000 int4 = 100000 ints exactly
    int4 z = {0, 0, 0, 0};
    reinterpret_cast<int4*>(cursor)[t] = z;
  }
  if (t < N_NODES * IN_F / 8) {
    float4 a = reinterpret_cast<const float4*>(x)[t * 2];
    float4 b = reinterpret_cast<const float4*>(x)[t * 2 + 1];
    uint4 o;
    o.x = (unsigned)f2bf(a.x) | ((unsigned)f2bf(a.y) << 16);
    o.y = (unsigned)f2bf(a.z) | ((unsigned)f2bf(a.w) << 16);
    o.z = (unsigned)f2bf(b.x) | ((unsigned)f2bf(b.y) << 16);
    o.w = (unsigned)f2bf(b.z) | ((unsigned)f2bf(b.w) << 16);
    reinterpret_cast<uint4*>(xb)[t] = o;
  } else {
    int idx = t - N_NODES * IN_F / 8;
    if (idx < 4096) {  // 2 tables x 16384 elems / 8
      int e0 = idx * 8;
      int table = e0 >> 14;
      int ee0 = e0 & 16383;
      int col = ee0 >> 7, k0 = ee0 & 127;  // k0 multiple of 8
      unsigned short tmp[8];
#pragma unroll
      for (int q = 0; q < 8; ++q) {
        int k = k0 + q;
        float v;
        if (table == 0)
          v = (k < 64) ? Ws1[k * HID + col] : Wn1[(k - 64) * HID + col];
        else
          v = (col < 64) ? Wn2[k * OUT_F + col] : Ws2[k * OUT_F + (col - 64)];
        tmp[q] = f2bf(v);
      }
      unsigned short* dst = (table == 0 ? wb1 : wb2) + ee0;
      *reinterpret_cast<uint4*>(dst) = *reinterpret_cast<const uint4*>(tmp);
    }
  }
}

// ---------------------------------------------------------------------------
// pass1: pos16[e] = cursor[dst]++  (atomic pass gives rank AND histogram)
// ---------------------------------------------------------------------------
__global__ __launch_bounds__(256) void pass1_kernel(
    const int* __restrict__ edst, int* __restrict__ cursor,
    unsigned short* __restrict__ pos16) {
  int t = blockIdx.x * 256 + threadIdx.x;
  if (t >= N_EDGES / 4) return;
  int4 d = reinterpret_cast<const int4*>(edst)[t];
  ushort4 p;
  p.x = (unsigned short)atomicAdd(cursor + d.x, 1);
  p.y = (unsigned short)atomicAdd(cursor + d.y, 1);
  p.z = (unsigned short)atomicAdd(cursor + d.z, 1);
  p.w = (unsigned short)atomicAdd(cursor + d.w, 1);
  reinterpret_cast<ushort4*>(pos16)[t] = p;
}

// ---------------------------------------------------------------------------
// hierarchical scan over cursor (= degrees): blocksum -> scanb -> writerow
// ---------------------------------------------------------------------------
__global__ __launch_bounds__(256) void blocksum_kernel(
    const int* __restrict__ degi, int* __restrict__ bsum) {
  __shared__ int ls[256];
  int i = blockIdx.x * 256 + threadIdx.x;
  ls[threadIdx.x] = (i < N_NODES) ? degi[i] : 0;
  __syncthreads();
  for (int off = 128; off > 0; off >>= 1) {
    if (threadIdx.x < off) ls[threadIdx.x] += ls[threadIdx.x + off];
    __syncthreads();
  }
  if (threadIdx.x == 0) bsum[blockIdx.x] = ls[0];
}

// also zeroes bnsum (used later by bnstats) to avoid a memset dispatch
__global__ __launch_bounds__(512) void scanb_kernel(
    const int* __restrict__ bsum, int* __restrict__ boff,
    int* __restrict__ rowstart, float* __restrict__ bnsum) {
  __shared__ int ls[512];
  int t = threadIdx.x;
  if (t < 256) bnsum[t] = 0.f;
  int v = (t < SCAN_NBLK) ? bsum[t] : 0;
  ls[t] = v;
  __syncthreads();
  for (int off = 1; off < 512; off <<= 1) {
    int u = (t >= off) ? ls[t - off] : 0;
    __syncthreads();
    ls[t] += u;
    __syncthreads();
  }
  if (t < SCAN_NBLK) boff[t] = ls[t] - v;  // exclusive
  if (t == 511) rowstart[N_NODES] = ls[511];
}

__global__ __launch_bounds__(256) void writerow_kernel(
    const int* __restrict__ degi, const int* __restrict__ boff,
    int* __restrict__ rowstart) {
  __shared__ int ls[256];
  int i = blockIdx.x * 256 + threadIdx.x;
  int t = threadIdx.x;
  int v = (i < N_NODES) ? degi[i] : 0;
  ls[t] = v;
  __syncthreads();
  for (int off = 1; off < 256; off <<= 1) {
    int u = (t >= off) ? ls[t - off] : 0;
    __syncthreads();
    ls[t] += u;
    __syncthreads();
  }
  if (i < N_NODES) rowstart[i] = boff[blockIdx.x] + ls[t] - v;
}

// ---------------------------------------------------------------------------
// scatter: csr[rowstart[dst] + pos16[e]] = src   (plain stores)
// ---------------------------------------------------------------------------
__global__ __launch_bounds__(256) void scatter_kernel(
    const int* __restrict__ esrc, const int* __restrict__ edst,
    const unsigned short* __restrict__ pos16,
    const int* __restrict__ rowstart, int* __restrict__ csr) {
  int t = blockIdx.x * 256 + threadIdx.x;
  if (t >= N_EDGES / 4) return;
  int4 s = reinterpret_cast<const int4*>(esrc)[t];
  int4 d = reinterpret_cast<const int4*>(edst)[t];
  ushort4 p = reinterpret_cast<const ushort4*>(pos16)[t];
  csr[rowstart[d.x] + p.x] = s.x;
  csr[rowstart[d.y] + p.y] = s.y;
  csr[rowstart[d.z] + p.z] = s.z;
  csr[rowstart[d.w] + p.w] = s.w;
}

// ---------------------------------------------------------------------------
// gemm1_fused: 64-row blocks, 256 thr. (a) gather mean_in(xb) -> aggl LDS;
// (b) hb = [xb | agg] @ wb1 + b1, B-fragments read from global wb1 (L1/L2-
// resident 32 KB). No weight LDS -> 9.2 KB LDS -> 8 blocks/CU for the gather.
// Wave w gathers rows [16w,16w+16) == rows its MFMA consumes; per-wave
// lgkmcnt(0) instead of a block barrier.
// ---------------------------------------------------------------------------
__global__ __launch_bounds__(256) void gemm1_fused(
    const unsigned short* __restrict__ xb, const int* __restrict__ rowstart,
    const int* __restrict__ csr, const unsigned short* __restrict__ wb,
    const float* __restrict__ b, unsigned short* __restrict__ hb) {
  __shared__ __align__(16) unsigned short aggl[64][72];
  int tid = threadIdx.x;

  // ---- gather phase: row r_local = tid>>2, 4 thr/row, 4-edge unroll ----
  {
    int r_local = tid >> 2;
    int jj = tid & 3;
    int row = blockIdx.x * 64 + r_local;
    float acc[16];
#pragma unroll
    for (int e = 0; e < 16; ++e) acc[e] = 0.f;
    if (row < N_NODES) {
      int r0 = rowstart[row];
      int r1 = rowstart[row + 1];
      int i = r0;
      for (; i + 3 < r1; i += 4) {
        int s0 = csr[i], s1 = csr[i + 1], s2 = csr[i + 2], s3 = csr[i + 3];
        const uint4* p0 =
            reinterpret_cast<const uint4*>(xb + (size_t)s0 * 64 + jj * 16);
        const uint4* p1 =
            reinterpret_cast<const uint4*>(xb + (size_t)s1 * 64 + jj * 16);
        const uint4* p2 =
            reinterpret_cast<const uint4*>(xb + (size_t)s2 * 64 + jj * 16);
        const uint4* p3 =
            reinterpret_cast<const uint4*>(xb + (size_t)s3 * 64 + jj * 16);
        uint4 a0 = p0[0], b0 = p0[1];
        uint4 a1 = p1[0], b1 = p1[1];
        uint4 a2 = p2[0], b2 = p2[1];
        uint4 a3 = p3[0], b3 = p3[1];
        acc[0] += (bflo(a0.x) + bflo(a1.x)) + (bflo(a2.x) + bflo(a3.x));
        acc[1] += (bfhi(a0.x) + bfhi(a1.x)) + (bfhi(a2.x) + bfhi(a3.x));
        acc[2] += (bflo(a0.y) + bflo(a1.y)) + (bflo(a2.y) + bflo(a3.y));
        acc[3] += (bfhi(a0.y) + bfhi(a1.y)) + (bfhi(a2.y) + bfhi(a3.y));
        acc[4] += (bflo(a0.z) + bflo(a1.z)) + (bflo(a2.z) + bflo(a3.z));
        acc[5] += (bfhi(a0.z) + bfhi(a1.z)) + (bfhi(a2.z) + bfhi(a3.z));
        acc[6] += (bflo(a0.w) + bflo(a1.w)) + (bflo(a2.w) + bflo(a3.w));
        acc[7] += (bfhi(a0.w) + bfhi(a1.w)) + (bfhi(a2.w) + bfhi(a3.w));
        acc[8] += (bflo(b0.x) + bflo(b1.x)) + (bflo(b2.x) + bflo(b3.x));
        acc[9] += (bfhi(b0.x) + bfhi(b1.x)) + (bfhi(b2.x) + bfhi(b3.x));
        acc[10] += (bflo(b0.y) + bflo(b1.y)) + (bflo(b2.y) + bflo(b3.y));
        acc[11] += (bfhi(b0.y) + bfhi(b1.y)) + (bfhi(b2.y) + bfhi(b3.y));
        acc[12] += (bflo(b0.z) + bflo(b1.z)) + (bflo(b2.z) + bflo(b3.z));
        acc[13] += (bfhi(b0.z) + bfhi(b1.z)) + (bfhi(b2.z) + bfhi(b3.z));
        acc[14] += (bflo(b0.w) + bflo(b1.w)) + (bflo(b2.w) + bflo(b3.w));
        acc[15] += (bfhi(b0.w) + bfhi(b1.w)) + (bfhi(b2.w) + bfhi(b3.w));
      }
      for (; i < r1; ++i) {
        int s0 = csr[i];
        const uint4* p0 =
            reinterpret_cast<const uint4*>(xb + (size_t)s0 * 64 + jj * 16);
        uint4 a0 = p0[0], b0 = p0[1];
        acc[0] += bflo(a0.x);
        acc[1] += bfhi(a0.x);
        acc[2] += bflo(a0.y);
        acc[3] += bfhi(a0.y);
        acc[4] += bflo(a0.z);
        acc[5] += bfhi(a0.z);
        acc[6] += bflo(a0.w);
        acc[7] += bfhi(a0.w);
        acc[8] += bflo(b0.x);
        acc[9] += bfhi(b0.x);
        acc[10] += bflo(b0.y);
        acc[11] += bfhi(b0.y);
        acc[12] += bflo(b0.z);
        acc[13] += bfhi(b0.z);
        acc[14] += bflo(b0.w);
        acc[15] += bfhi(b0.w);
      }
      int deg = r1 - r0;
      float rd = 1.0f / (float)(deg > 0 ? deg : 1);
#pragma unroll
      for (int e = 0; e < 16; ++e) acc[e] *= rd;
    }
    uint4 o0, o1;
    o0.x = (unsigned)f2bf(acc[0]) | ((unsigned)f2bf(acc[1]) << 16);
    o0.y = (unsigned)f2bf(acc[2]) | ((unsigned)f2bf(acc[3]) << 16);
    o0.z = (unsigned)f2bf(acc[4]) | ((unsigned)f2bf(acc[5]) << 16);
    o0.w = (unsigned)f2bf(acc[6]) | ((unsigned)f2bf(acc[7]) << 16);
    o1.x = (unsigned)f2bf(acc[8]) | ((unsigned)f2bf(acc[9]) << 16);
    o1.y = (unsigned)f2bf(acc[10]) | ((unsigned)f2bf(acc[11]) << 16);
    o1.z = (unsigned)f2bf(acc[12]) | ((unsigned)f2bf(acc[13]) << 16);
    o1.w = (unsigned)f2bf(acc[14]) | ((unsigned)f2bf(acc[15]) << 16);
    uint4* dst = reinterpret_cast<uint4*>(&aggl[r_local][jj * 16]);
    dst[0] = o0;
    dst[1] = o1;
  }
  // Same-wave producer/consumer: drain this wave's LDS writes.
  asm volatile("s_waitcnt lgkmcnt(0)" ::: "memory");

  // ---- MFMA phase: 4 waves x 16 rows ----
  int wave = tid >> 6, lane = tid & 63;
  int m = lane & 15, kg = lane >> 4;
  int rbase = blockIdx.x * 64 + wave * 16;
  int rowa = rbase + m;
  if (rowa >= N_NODES) rowa = N_NODES - 1;  // clamp (stores guarded)
  int lr = wave * 16 + m;                   // local row for aggl

  short8v a[4];
#pragma unroll
  for (int kt = 0; kt < 4; ++kt) {
    int c0 = kt * 32 + kg * 8;
    if (c0 < 64) {
      a[kt] = *reinterpret_cast<const short8v*>(xb + (size_t)rowa * 64 + c0);
    } else {
      a[kt] = *reinterpret_cast<const short8v*>(&aggl[lr][c0 - 64]);
    }
  }

  f32x4 acc[8];
#pragma unroll
  for (int nt = 0; nt < 8; ++nt) acc[nt] = (f32x4){0.f, 0.f, 0.f, 0.f};

#pragma unroll
  for (int nt = 0; nt < 8; ++nt) {
    int col = nt * 16 + m;
    const unsigned short* wcol = wb + ((size_t)col << 7);
#pragma unroll
    for (int kt = 0; kt < 4; ++kt) {
      short8v bf =
          *reinterpret_cast<const short8v*>(wcol + kt * 32 + kg * 8);
      acc[nt] = __builtin_amdgcn_mfma_f32_16x16x32_bf16(a[kt], bf, acc[nt], 0, 0, 0);
    }
  }

#pragma unroll
  for (int nt = 0; nt < 8; ++nt) {
    int col = nt * 16 + m;
    float bias = b[col];
#pragma unroll
    for (int r = 0; r < 4; ++r) {
      int rr = rbase + kg * 4 + r;
      if (rr < N_NODES) hb[(size_t)rr * HID + col] = f2bf(acc[nt][r] + bias);
    }
  }
}

// ---------------------------------------------------------------------------
// aggb2: out[n] = bf16_s[n] + mean(zb over in-edges)  (write-once fp32 out)
// ---------------------------------------------------------------------------
__global__ __launch_bounds__(256) void aggb2_kernel(
    const unsigned short* __restrict__ zb, const unsigned short* __restrict__ sb,
    const int* __restrict__ rowstart, const int* __restrict__ csr,
    float* __restrict__ out) {
  int n = blockIdx.x * 32 + (threadIdx.x >> 3);
  int j = threadIdx.x & 7;
  if (n >= N_NODES) return;
  int r0 = rowstart[n];
  int r1 = rowstart[n + 1];
  float acc[8] = {0.f, 0.f, 0.f, 0.f, 0.f, 0.f, 0.f, 0.f};
  int i = r0;
  for (; i + 3 < r1; i += 4) {
    int s0 = csr[i], s1 = csr[i + 1], s2 = csr[i + 2], s3 = csr[i + 3];
    uint4 v0 = *reinterpret_cast<const uint4*>(zb + (size_t)s0 * 64 + j * 8);
    uint4 v1 = *reinterpret_cast<const uint4*>(zb + (size_t)s1 * 64 + j * 8);
    uint4 v2 = *reinterpret_cast<const uint4*>(zb + (size_t)s2 * 64 + j * 8);
    uint4 v3 = *reinterpret_cast<const uint4*>(zb + (size_t)s3 * 64 + j * 8);
    acc[0] += (bflo(v0.x) + bflo(v1.x)) + (bflo(v2.x) + bflo(v3.x));
    acc[1] += (bfhi(v0.x) + bfhi(v1.x)) + (bfhi(v2.x) + bfhi(v3.x));
    acc[2] += (bflo(v0.y) + bflo(v1.y)) + (bflo(v2.y) + bflo(v3.y));
    acc[3] += (bfhi(v0.y) + bfhi(v1.y)) + (bfhi(v2.y) + bfhi(v3.y));
    acc[4] += (bflo(v0.z) + bflo(v1.z)) + (bflo(v2.z) + bflo(v3.z));
    acc[5] += (bfhi(v0.z) + bfhi(v1.z)) + (bfhi(v2.z) + bfhi(v3.z));
    acc[6] += (bflo(v0.w) + bflo(v1.w)) + (bflo(v2.w) + bflo(v3.w));
    acc[7] += (bfhi(v0.w) + bfhi(v1.w)) + (bfhi(v2.w) + bfhi(v3.w));
  }
  for (; i < r1; ++i) {
    int s0 = csr[i];
    uint4 v0 = *reinterpret_cast<const uint4*>(zb + (size_t)s0 * 64 + j * 8);
    acc[0] += bflo(v0.x);
    acc[1] += bfhi(v0.x);
    acc[2] += bflo(v0.y);
    acc[3] += bfhi(v0.y);
    acc[4] += bflo(v0.z);
    acc[5] += bfhi(v0.z);
    acc[6] += bflo(v0.w);
    acc[7] += bfhi(v0.w);
  }
  int deg = r1 - r0;
  float rd = 1.0f / (float)(deg > 0 ? deg : 1);
  uint4 sv = *reinterpret_cast<const uint4*>(sb + (size_t)n * 64 + j * 8);
  float* dp = out + (size_t)n * 64 + j * 8;
  __builtin_nontemporal_store(bflo(sv.x) + acc[0] * rd, dp + 0);
  __builtin_nontemporal_store(bfhi(sv.x) + acc[1] * rd, dp + 1);
  __builtin_nontemporal_store(bflo(sv.y) + acc[2] * rd, dp + 2);
  __builtin_nontemporal_store(bfhi(sv.y) + acc[3] * rd, dp + 3);
  __builtin_nontemporal_store(bflo(sv.z) + acc[4] * rd, dp + 4);
  __builtin_nontemporal_store(bfhi(sv.z) + acc[5] * rd, dp + 5);
  __builtin_nontemporal_store(bflo(sv.w) + acc[6] * rd, dp + 6);
  __builtin_nontemporal_store(bfhi(sv.w) + acc[7] * rd, dp + 7);
}

// ---------------------------------------------------------------------------
// bnstats: per-feature sum/sumsq over nodes, uint4-vectorized.
// ---------------------------------------------------------------------------
__global__ __launch_bounds__(256) void bnstats_kernel(
    const unsigned short* __restrict__ hb, float* __restrict__ bnsum) {
  int j = threadIdx.x & 15;   // feature block (8 feats)
  int g = threadIdx.x >> 4;   // row group 0..15
  float s[8] = {0.f, 0.f, 0.f, 0.f, 0.f, 0.f, 0.f, 0.f};
  float q[8] = {0.f, 0.f, 0.f, 0.f, 0.f, 0.f, 0.f, 0.f};
  for (int r = blockIdx.x * 16 + g; r < N_NODES; r += gridDim.x * 16) {
    uint4 v = *reinterpret_cast<const uint4*>(hb + (size_t)r * HID + j * 8);
    float f0 = bflo(v.x), f1 = bfhi(v.x), f2 = bflo(v.y), f3 = bfhi(v.y);
    float f4 = bflo(v.z), f5 = bfhi(v.z), f6 = bflo(v.w), f7 = bfhi(v.w);
    s[0] += f0; q[0] += f0 * f0;
    s[1] += f1; q[1] += f1 * f1;
    s[2] += f2; q[2] += f2 * f2;
    s[3] += f3; q[3] += f3 * f3;
    s[4] += f4; q[4] += f4 * f4;
    s[5] += f5; q[5] += f5 * f5;
    s[6] += f6; q[6] += f6 * f6;
    s[7] += f7; q[7] += f7 * f7;
  }
  __shared__ float lss[256 * 8];
  __shared__ float lqq[256 * 8];
#pragma unroll
  for (int e = 0; e < 8; ++e) {
    lss[threadIdx.x * 8 + e] = s[e];
    lqq[threadIdx.x * 8 + e] = q[e];
  }
  __syncthreads();
  if (threadIdx.x < 128) {
    int f = threadIdx.x;
    int jj = f >> 3, e = f & 7;
    float S = 0.f, Q = 0.f;
#pragma unroll
    for (int gg = 0; gg < 16; ++gg) {
      S += lss[(gg * 16 + jj) * 8 + e];
      Q += lqq[(gg * 16 + jj) * 8 + e];
    }
    unsafeAtomicAdd(bnsum + f, S);
    unsafeAtomicAdd(bnsum + 128 + f, Q);
  }
}

// ---------------------------------------------------------------------------
// gemm2_mfma: 64-row blocks, 256 thr; scale/shift from bnsum inline;
// hbn = relu(bn(hb)); [z|s] = hbn @ wb2 (global B-fragments); zb/sb bf16.
// ---------------------------------------------------------------------------
__global__ __launch_bounds__(256) void gemm2_mfma(
    const unsigned short* __restrict__ hb, const float* __restrict__ bnsum,
    const float* __restrict__ gamma, const float* __restrict__ beta,
    const unsigned short* __restrict__ wb, const float* __restrict__ b,
    unsigned short* __restrict__ zb, unsigned short* __restrict__ sb) {
  __shared__ float scs[HID];
  __shared__ float shs[HID];
  int tid = threadIdx.x;
  if (tid < HID) {  // bnfinal inline
    const float invn = 1.0f / (float)N_NODES;
    float mu = bnsum[tid] * invn;
    float var = bnsum[128 + tid] * invn - mu * mu;
    float sc = gamma[tid] * rsqrtf(var + BN_EPS);
    scs[tid] = sc;
    shs[tid] = beta[tid] - mu * sc;
  }
  __syncthreads();

  int wave = tid >> 6, lane = tid & 63;
  int m = lane & 15, kg = lane >> 4;
  int rbase = blockIdx.x * 64 + wave * 16;
  int rowa = rbase + m;
  if (rowa >= N_NODES) rowa = N_NODES - 1;

  short8v a[4];
#pragma unroll
  for (int kt = 0; kt < 4; ++kt) {
    int c0 = kt * 32 + kg * 8;
    uint4 raw = *reinterpret_cast<const uint4*>(hb + (size_t)rowa * HID + c0);
    float4 sc0 = *reinterpret_cast<const float4*>(&scs[c0]);
    float4 sc1 = *reinterpret_cast<const float4*>(&scs[c0 + 4]);
    float4 sh0 = *reinterpret_cast<const float4*>(&shs[c0]);
    float4 sh1 = *reinterpret_cast<const float4*>(&shs[c0 + 4]);
    short8v av;
    av[0] = (short)f2bf(fmaxf(bflo(raw.x) * sc0.x + sh0.x, 0.f));
    av[1] = (short)f2bf(fmaxf(bfhi(raw.x) * sc0.y + sh0.y, 0.f));
    av[2] = (short)f2bf(fmaxf(bflo(raw.y) * sc0.z + sh0.z, 0.f));
    av[3] = (short)f2bf(fmaxf(bfhi(raw.y) * sc0.w + sh0.w, 0.f));
    av[4] = (short)f2bf(fmaxf(bflo(raw.z) * sc1.x + sh1.x, 0.f));
    av[5] = (short)f2bf(fmaxf(bfhi(raw.z) * sc1.y + sh1.y, 0.f));
    av[6] = (short)f2bf(fmaxf(bflo(raw.w) * sc1.z + sh1.z, 0.f));
    av[7] = (short)f2bf(fmaxf(bfhi(raw.w) * sc1.w + sh1.w, 0.f));
    a[kt] = av;
  }

  f32x4 acc[8];
#pragma unroll
  for (int nt = 0; nt < 8; ++nt) acc[nt] = (f32x4){0.f, 0.f, 0.f, 0.f};

#pragma unroll
  for (int nt = 0; nt < 8; ++nt) {
    int col = nt * 16 + m;
    const unsigned short* wcol = wb + ((size_t)col << 7);
#pragma unroll
    for (int kt = 0; kt < 4; ++kt) {
      short8v bf =
          *reinterpret_cast<const short8v*>(wcol + kt * 32 + kg * 8);
      acc[nt] = __builtin_amdgcn_mfma_f32_16x16x32_bf16(a[kt], bf, acc[nt], 0, 0, 0);
    }
  }

#pragma unroll
  for (int nt = 0; nt < 8; ++nt) {
    int col = nt * 16 + m;
#pragma unroll
    for (int r = 0; r < 4; ++r) {
      int rr = rbase + kg * 4 + r;
      if (rr < N_NODES) {
        float v = acc[nt][r];
        if (col < 64)
          zb[(size_t)rr * OUT_F + col] = f2bf(v);
        else
          sb[(size_t)rr * OUT_F + (col - 64)] = f2bf(v + b[col - 64]);
      }
    }
  }
}

// ---------------------------------------------------------------------------
extern "C" void kernel_launch(void* const* d_in, const int* in_sizes, int n_in,
                              void* d_out, int out_size, void* d_ws,
                              size_t ws_size, hipStream_t stream) {
  const float* x = (const float*)d_in[0];
  const int* esrc = (const int*)d_in[1];
  const int* edst = (const int*)d_in[2];
  const float* Ws1 = (const float*)d_in[3];
  const float* Wn1 = (const float*)d_in[4];
  const float* b1 = (const float*)d_in[5];
  const float* gamma = (const float*)d_in[6];
  const float* beta = (const float*)d_in[7];
  const float* Ws2 = (const float*)d_in[8];
  const float* Wn2 = (const float*)d_in[9];
  const float* b2 = (const float*)d_in[10];
  float* out = (float*)d_out;

  float* ws = (float*)d_ws;
  float* bnsum = ws;                               // 256
  unsigned short* wb1 = (unsigned short*)(ws + 256);   // 16384 shorts
  unsigned short* wb2 = (unsigned short*)(ws + 8448);  // 16384 shorts
  int* cursor = (int*)(ws + 16640);                // N (degrees after pass1)
  int* rowstart = cursor + N_NODES;                // N+1
  int* bsum = rowstart + N_NODES + 1;              // SCAN_NBLK
  int* boff = bsum + SCAN_NBLK;                    // SCAN_NBLK
  int* csr = boff + SCAN_NBLK;                     // E
  int pos16_off =
      ((16640 + 2 * N_NODES + 1 + 2 * SCAN_NBLK + N_EDGES) + 3) & ~3;
  unsigned short* pos16 = (unsigned short*)(ws + pos16_off);  // E ushort
  unsigned short* xb = (unsigned short*)(ws + pos16_off + N_EDGES / 2);
  unsigned short* zbuf = xb + (size_t)N_NODES * 64;           // N*64
  unsigned short* sb = zbuf + (size_t)N_NODES * 64;           // N*64
  unsigned short* hb = sb + (size_t)N_NODES * 64;             // N*128

  const int e4grid = (N_EDGES / 4 + 255) / 256;
  // prep: 3125 blocks for xb + 16 blocks for W tables
  prep_kernel<<<(N_NODES * IN_F / 8 + 4096 + 255) / 256, 256, 0, stream>>>(
      x, Ws1, Wn1, Wn2, Ws2, xb, wb1, wb2, cursor);
  pass1_kernel<<<e4grid, 256, 0, stream>>>(edst, cursor, pos16);
  blocksum_kernel<<<SCAN_NBLK, 256, 0, stream>>>(cursor, bsum);
  scanb_kernel<<<1, 512, 0, stream>>>(bsum, boff, rowstart, bnsum);
  writerow_kernel<<<SCAN_NBLK, 256, 0, stream>>>(cursor, boff, rowstart);
  scatter_kernel<<<e4grid, 256, 0, stream>>>(esrc, edst, pos16, rowstart, csr);

  const int ggrid = (N_NODES + 63) / 64;
  const int agrid = (N_NODES + 31) / 32;
  // layer 1 (fused): hb = [xb | mean_in(xb)] @ wb1 + b1
  gemm1_fused<<<ggrid, 256, 0, stream>>>(xb, rowstart, csr, wb1, b1, hb);

  // batchnorm stats (finalize folded into gemm2 prologue)
  bnstats_kernel<<<256, 256, 0, stream>>>(hb, bnsum);

  // layer 2: [zb|sb] = relu(bn(hb)) @ wb2; out = sb + mean_in(zb)
  gemm2_mfma<<<ggrid, 256, 0, stream>>>(hb, bnsum, gamma, beta, wb2, b2, zbuf,
                                        sb);
  aggb2_kernel<<<agrid, 256, 0, stream>>>(zbuf, sb, rowstart, csr, out);
}

// Round 17
// 174.566 us; speedup vs baseline: 1.2300x; 1.2300x over previous
//
#include <hip/hip_runtime.h>

#define N_NODES 100000
#define N_EDGES 800000
#define IN_F 64
#define HID 128
#define OUT_F 64
#define BN_EPS 1e-5f
#define SCAN_NBLK ((N_NODES + 255) / 256)  // 391

typedef __attribute__((ext_vector_type(8))) short short8v;
typedef __attribute__((ext_vector_type(4))) float f32x4;

static __device__ __forceinline__ unsigned short f2bf(float f) {
  unsigned u = __float_as_uint(f);
  return (unsigned short)((u + 0x7FFFu + ((u >> 16) & 1u)) >> 16);
}
static __device__ __forceinline__ float bflo(unsigned u) {
  return __uint_as_float(u << 16);
}
static __device__ __forceinline__ float bfhi(unsigned u) {
  return __uint_as_float(u & 0xFFFF0000u);
}

// ---------------------------------------------------------------------------
// cvtzero: xb = bf16(x) (8 elems/thread) + zero cursor (first 25000 threads)
// ---------------------------------------------------------------------------
__global__ __launch_bounds__(256) void cvtzero_kernel(
    const float* __restrict__ x, unsigned short* __restrict__ xb,
    int* __restrict__ cursor) {
  int t = blockIdx.x * 256 + threadIdx.x;
  if (t < N_NODES / 4) {  // 25000 int4 = 100000 ints exactly
    int4 z = {0, 0, 0, 0};
    reinterpret_cast<int4*>(cursor)[t] = z;
  }
  if (t >= N_NODES * IN_F / 8) return;
  float4 a = reinterpret_cast<const float4*>(x)[t * 2];
  float4 b = reinterpret_cast<const float4*>(x)[t * 2 + 1];
  uint4 o;
  o.x = (unsigned)f2bf(a.x) | ((unsigned)f2bf(a.y) << 16);
  o.y = (unsigned)f2bf(a.z) | ((unsigned)f2bf(a.w) << 16);
  o.z = (unsigned)f2bf(b.x) | ((unsigned)f2bf(b.y) << 16);
  o.w = (unsigned)f2bf(b.z) | ((unsigned)f2bf(b.w) << 16);
  reinterpret_cast<uint4*>(xb)[t] = o;
}

// ---------------------------------------------------------------------------
// pass1: pos16[e] = cursor[dst]++  (atomic pass gives rank AND histogram)
// ---------------------------------------------------------------------------
__global__ __launch_bounds__(256) void pass1_kernel(
    const int* __restrict__ edst, int* __restrict__ cursor,
    unsigned short* __restrict__ pos16) {
  int t = blockIdx.x * 256 + threadIdx.x;
  if (t >= N_EDGES / 4) return;
  int4 d = reinterpret_cast<const int4*>(edst)[t];
  ushort4 p;
  p.x = (unsigned short)atomicAdd(cursor + d.x, 1);
  p.y = (unsigned short)atomicAdd(cursor + d.y, 1);
  p.z = (unsigned short)atomicAdd(cursor + d.z, 1);
  p.w = (unsigned short)atomicAdd(cursor + d.w, 1);
  reinterpret_cast<ushort4*>(pos16)[t] = p;
}

// ---------------------------------------------------------------------------
// hierarchical scan over cursor (= degrees): blocksum -> scanb -> writerow
// ---------------------------------------------------------------------------
__global__ __launch_bounds__(256) void blocksum_kernel(
    const int* __restrict__ degi, int* __restrict__ bsum) {
  __shared__ int ls[256];
  int i = blockIdx.x * 256 + threadIdx.x;
  ls[threadIdx.x] = (i < N_NODES) ? degi[i] : 0;
  __syncthreads();
  for (int off = 128; off > 0; off >>= 1) {
    if (threadIdx.x < off) ls[threadIdx.x] += ls[threadIdx.x + off];
    __syncthreads();
  }
  if (threadIdx.x == 0) bsum[blockIdx.x] = ls[0];
}

// also zeroes bnsum (used later by bnstats) to avoid a memset dispatch
__global__ __launch_bounds__(512) void scanb_kernel(
    const int* __restrict__ bsum, int* __restrict__ boff,
    int* __restrict__ rowstart, float* __restrict__ bnsum) {
  __shared__ int ls[512];
  int t = threadIdx.x;
  if (t < 256) bnsum[t] = 0.f;
  int v = (t < SCAN_NBLK) ? bsum[t] : 0;
  ls[t] = v;
  __syncthreads();
  for (int off = 1; off < 512; off <<= 1) {
    int u = (t >= off) ? ls[t - off] : 0;
    __syncthreads();
    ls[t] += u;
    __syncthreads();
  }
  if (t < SCAN_NBLK) boff[t] = ls[t] - v;  // exclusive
  if (t == 511) rowstart[N_NODES] = ls[511];
}

__global__ __launch_bounds__(256) void writerow_kernel(
    const int* __restrict__ degi, const int* __restrict__ boff,
    int* __restrict__ rowstart) {
  __shared__ int ls[256];
  int i = blockIdx.x * 256 + threadIdx.x;
  int t = threadIdx.x;
  int v = (i < N_NODES) ? degi[i] : 0;
  ls[t] = v;
  __syncthreads();
  for (int off = 1; off < 256; off <<= 1) {
    int u = (t >= off) ? ls[t - off] : 0;
    __syncthreads();
    ls[t] += u;
    __syncthreads();
  }
  if (i < N_NODES) rowstart[i] = boff[blockIdx.x] + ls[t] - v;
}

// ---------------------------------------------------------------------------
// scatter: csr[rowstart[dst] + pos16[e]] = src   (plain stores; csr is
// re-read by the agg kernels soon after -> keep it cacheable)
// ---------------------------------------------------------------------------
__global__ __launch_bounds__(256) void scatter_kernel(
    const int* __restrict__ esrc, const int* __restrict__ edst,
    const unsigned short* __restrict__ pos16,
    const int* __restrict__ rowstart, int* __restrict__ csr) {
  int t = blockIdx.x * 256 + threadIdx.x;
  if (t >= N_EDGES / 4) return;
  int4 s = reinterpret_cast<const int4*>(esrc)[t];
  int4 d = reinterpret_cast<const int4*>(edst)[t];
  ushort4 p = reinterpret_cast<const ushort4*>(pos16)[t];
  csr[rowstart[d.x] + p.x] = s.x;
  csr[rowstart[d.y] + p.y] = s.y;
  csr[rowstart[d.z] + p.z] = s.z;
  csr[rowstart[d.w] + p.w] = s.w;
}

// ---------------------------------------------------------------------------
// gemm1_fused: per 128-row block: (a) gather mean_in(xb) -> LDS (bf16),
// (b) hb = [xb | agg] @ [Ws1 ; Wn1] + b1 via MFMA.
// Gather: 4 thr/row x 16 feats (2 uint4/edge), fp32 acc, 2-edge unroll.
// aggl padded [128][72] -> 2-way bank alias on ds_read_b128 (free).
// ---------------------------------------------------------------------------
__global__ __launch_bounds__(512) void gemm1_fused(
    const unsigned short* __restrict__ xb, const int* __restrict__ rowstart,
    const int* __restrict__ csr, const float* __restrict__ Ws,
    const float* __restrict__ Wn, const float* __restrict__ b,
    unsigned short* __restrict__ hb) {
  __shared__ __align__(16) unsigned short wt[128 * 128];  // 32 KB swizzled W
  __shared__ __align__(16) unsigned short aggl[128][72];  // 18 KB agg tile
  __shared__ float bs[HID];
  int tid = threadIdx.x;
  for (int i = tid; i < 128 * 128; i += 512) {
    int k = i >> 7, j = i & 127;
    float v = (k < 64) ? Ws[k * HID + j] : Wn[(k - 64) * HID + j];
    int idx = (j << 7) | k;
    wt[idx ^ ((j & 15) << 3)] = f2bf(v);
  }
  if (tid < HID) bs[tid] = b[tid];

  // ---- gather phase: row r_local, feats jj*16..jj*16+15 ----
  {
    int r_local = tid >> 2;
    int jj = tid & 3;
    int row = blockIdx.x * 128 + r_local;
    float acc[16];
#pragma unroll
    for (int e = 0; e < 16; ++e) acc[e] = 0.f;
    if (row < N_NODES) {
      int r0 = rowstart[row];
      int r1 = rowstart[row + 1];
      int i = r0;
      for (; i + 1 < r1; i += 2) {
        int s0 = csr[i], s1 = csr[i + 1];
        const uint4* p0 =
            reinterpret_cast<const uint4*>(xb + (size_t)s0 * 64 + jj * 16);
        const uint4* p1 =
            reinterpret_cast<const uint4*>(xb + (size_t)s1 * 64 + jj * 16);
        uint4 a0 = p0[0], b0 = p0[1];
        uint4 a1 = p1[0], b1 = p1[1];
        acc[0] += bflo(a0.x) + bflo(a1.x);
        acc[1] += bfhi(a0.x) + bfhi(a1.x);
        acc[2] += bflo(a0.y) + bflo(a1.y);
        acc[3] += bfhi(a0.y) + bfhi(a1.y);
        acc[4] += bflo(a0.z) + bflo(a1.z);
        acc[5] += bfhi(a0.z) + bfhi(a1.z);
        acc[6] += bflo(a0.w) + bflo(a1.w);
        acc[7] += bfhi(a0.w) + bfhi(a1.w);
        acc[8] += bflo(b0.x) + bflo(b1.x);
        acc[9] += bfhi(b0.x) + bfhi(b1.x);
        acc[10] += bflo(b0.y) + bflo(b1.y);
        acc[11] += bfhi(b0.y) + bfhi(b1.y);
        acc[12] += bflo(b0.z) + bflo(b1.z);
        acc[13] += bfhi(b0.z) + bfhi(b1.z);
        acc[14] += bflo(b0.w) + bflo(b1.w);
        acc[15] += bfhi(b0.w) + bfhi(b1.w);
      }
      if (i < r1) {
        int s0 = csr[i];
        const uint4* p0 =
            reinterpret_cast<const uint4*>(xb + (size_t)s0 * 64 + jj * 16);
        uint4 a0 = p0[0], b0 = p0[1];
        acc[0] += bflo(a0.x);
        acc[1] += bfhi(a0.x);
        acc[2] += bflo(a0.y);
        acc[3] += bfhi(a0.y);
        acc[4] += bflo(a0.z);
        acc[5] += bfhi(a0.z);
        acc[6] += bflo(a0.w);
        acc[7] += bfhi(a0.w);
        acc[8] += bflo(b0.x);
        acc[9] += bfhi(b0.x);
        acc[10] += bflo(b0.y);
        acc[11] += bfhi(b0.y);
        acc[12] += bflo(b0.z);
        acc[13] += bfhi(b0.z);
        acc[14] += bflo(b0.w);
        acc[15] += bfhi(b0.w);
      }
      int deg = r1 - r0;
      float rd = 1.0f / (float)(deg > 0 ? deg : 1);
#pragma unroll
      for (int e = 0; e < 16; ++e) acc[e] *= rd;
    }
    uint4 o0, o1;
    o0.x = (unsigned)f2bf(acc[0]) | ((unsigned)f2bf(acc[1]) << 16);
    o0.y = (unsigned)f2bf(acc[2]) | ((unsigned)f2bf(acc[3]) << 16);
    o0.z = (unsigned)f2bf(acc[4]) | ((unsigned)f2bf(acc[5]) << 16);
    o0.w = (unsigned)f2bf(acc[6]) | ((unsigned)f2bf(acc[7]) << 16);
    o1.x = (unsigned)f2bf(acc[8]) | ((unsigned)f2bf(acc[9]) << 16);
    o1.y = (unsigned)f2bf(acc[10]) | ((unsigned)f2bf(acc[11]) << 16);
    o1.z = (unsigned)f2bf(acc[12]) | ((unsigned)f2bf(acc[13]) << 16);
    o1.w = (unsigned)f2bf(acc[14]) | ((unsigned)f2bf(acc[15]) << 16);
    uint4* dst = reinterpret_cast<uint4*>(&aggl[r_local][jj * 16]);
    dst[0] = o0;
    dst[1] = o1;
  }
  __syncthreads();

  // ---- MFMA phase ----
  int wave = tid >> 6, lane = tid & 63;
  int m = lane & 15, kg = lane >> 4;
  int rbase = blockIdx.x * 128 + wave * 16;
  int rowa = rbase + m;
  if (rowa >= N_NODES) rowa = N_NODES - 1;  // clamp (stores guarded)
  int lr = wave * 16 + m;                   // local row for aggl

  short8v a[4];
#pragma unroll
  for (int kt = 0; kt < 4; ++kt) {
    int c0 = kt * 32 + kg * 8;
    if (c0 < 64) {
      a[kt] = *reinterpret_cast<const short8v*>(xb + (size_t)rowa * 64 + c0);
    } else {
      a[kt] = *reinterpret_cast<const short8v*>(&aggl[lr][c0 - 64]);
    }
  }

  f32x4 acc[8];
#pragma unroll
  for (int nt = 0; nt < 8; ++nt) acc[nt] = (f32x4){0.f, 0.f, 0.f, 0.f};

#pragma unroll
  for (int nt = 0; nt < 8; ++nt) {
    int col = nt * 16 + m;
    int base = col << 7;
    int sw = (col & 15) << 3;
#pragma unroll
    for (int kt = 0; kt < 4; ++kt) {
      int idx = (base | (kt * 32 + kg * 8)) ^ sw;
      short8v bf = *reinterpret_cast<const short8v*>(&wt[idx]);
      acc[nt] = __builtin_amdgcn_mfma_f32_16x16x32_bf16(a[kt], bf, acc[nt], 0, 0, 0);
    }
  }

#pragma unroll
  for (int nt = 0; nt < 8; ++nt) {
    int col = nt * 16 + m;
    float bias = bs[col];
#pragma unroll
    for (int r = 0; r < 4; ++r) {
      int rr = rbase + kg * 4 + r;
      if (rr < N_NODES) hb[(size_t)rr * HID + col] = f2bf(acc[nt][r] + bias);
    }
  }
}

// ---------------------------------------------------------------------------
// aggb2: out[n] = bf16_s[n] + mean(zb over in-edges)  (write-once fp32 out)
// 4-edge unroll; nontemporal stores only on out (never re-read).
// ---------------------------------------------------------------------------
__global__ __launch_bounds__(256) void aggb2_kernel(
    const unsigned short* __restrict__ zb, const unsigned short* __restrict__ sb,
    const int* __restrict__ rowstart, const int* __restrict__ csr,
    float* __restrict__ out) {
  int n = blockIdx.x * 32 + (threadIdx.x >> 3);
  int j = threadIdx.x & 7;
  if (n >= N_NODES) return;
  int r0 = rowstart[n];
  int r1 = rowstart[n + 1];
  float acc[8] = {0.f, 0.f, 0.f, 0.f, 0.f, 0.f, 0.f, 0.f};
  int i = r0;
  for (; i + 3 < r1; i += 4) {
    int s0 = csr[i], s1 = csr[i + 1], s2 = csr[i + 2], s3 = csr[i + 3];
    uint4 v0 = *reinterpret_cast<const uint4*>(zb + (size_t)s0 * 64 + j * 8);
    uint4 v1 = *reinterpret_cast<const uint4*>(zb + (size_t)s1 * 64 + j * 8);
    uint4 v2 = *reinterpret_cast<const uint4*>(zb + (size_t)s2 * 64 + j * 8);
    uint4 v3 = *reinterpret_cast<const uint4*>(zb + (size_t)s3 * 64 + j * 8);
    acc[0] += (bflo(v0.x) + bflo(v1.x)) + (bflo(v2.x) + bflo(v3.x));
    acc[1] += (bfhi(v0.x) + bfhi(v1.x)) + (bfhi(v2.x) + bfhi(v3.x));
    acc[2] += (bflo(v0.y) + bflo(v1.y)) + (bflo(v2.y) + bflo(v3.y));
    acc[3] += (bfhi(v0.y) + bfhi(v1.y)) + (bfhi(v2.y) + bfhi(v3.y));
    acc[4] += (bflo(v0.z) + bflo(v1.z)) + (bflo(v2.z) + bflo(v3.z));
    acc[5] += (bfhi(v0.z) + bfhi(v1.z)) + (bfhi(v2.z) + bfhi(v3.z));
    acc[6] += (bflo(v0.w) + bflo(v1.w)) + (bflo(v2.w) + bflo(v3.w));
    acc[7] += (bfhi(v0.w) + bfhi(v1.w)) + (bfhi(v2.w) + bfhi(v3.w));
  }
  for (; i < r1; ++i) {
    int s0 = csr[i];
    uint4 v0 = *reinterpret_cast<const uint4*>(zb + (size_t)s0 * 64 + j * 8);
    acc[0] += bflo(v0.x);
    acc[1] += bfhi(v0.x);
    acc[2] += bflo(v0.y);
    acc[3] += bfhi(v0.y);
    acc[4] += bflo(v0.z);
    acc[5] += bfhi(v0.z);
    acc[6] += bflo(v0.w);
    acc[7] += bfhi(v0.w);
  }
  int deg = r1 - r0;
  float rd = 1.0f / (float)(deg > 0 ? deg : 1);
  uint4 sv = *reinterpret_cast<const uint4*>(sb + (size_t)n * 64 + j * 8);
  float* dp = out + (size_t)n * 64 + j * 8;
  __builtin_nontemporal_store(bflo(sv.x) + acc[0] * rd, dp + 0);
  __builtin_nontemporal_store(bfhi(sv.x) + acc[1] * rd, dp + 1);
  __builtin_nontemporal_store(bflo(sv.y) + acc[2] * rd, dp + 2);
  __builtin_nontemporal_store(bfhi(sv.y) + acc[3] * rd, dp + 3);
  __builtin_nontemporal_store(bflo(sv.z) + acc[4] * rd, dp + 4);
  __builtin_nontemporal_store(bfhi(sv.z) + acc[5] * rd, dp + 5);
  __builtin_nontemporal_store(bflo(sv.w) + acc[6] * rd, dp + 6);
  __builtin_nontemporal_store(bfhi(sv.w) + acc[7] * rd, dp + 7);
}

// ---------------------------------------------------------------------------
// bnstats: per-feature sum/sumsq over nodes, uint4-vectorized.
// ---------------------------------------------------------------------------
__global__ __launch_bounds__(256) void bnstats_kernel(
    const unsigned short* __restrict__ hb, float* __restrict__ bnsum) {
  int j = threadIdx.x & 15;   // feature block (8 feats)
  int g = threadIdx.x >> 4;   // row group 0..15
  float s[8] = {0.f, 0.f, 0.f, 0.f, 0.f, 0.f, 0.f, 0.f};
  float q[8] = {0.f, 0.f, 0.f, 0.f, 0.f, 0.f, 0.f, 0.f};
  for (int r = blockIdx.x * 16 + g; r < N_NODES; r += gridDim.x * 16) {
    uint4 v = *reinterpret_cast<const uint4*>(hb + (size_t)r * HID + j * 8);
    float f0 = bflo(v.x), f1 = bfhi(v.x), f2 = bflo(v.y), f3 = bfhi(v.y);
    float f4 = bflo(v.z), f5 = bfhi(v.z), f6 = bflo(v.w), f7 = bfhi(v.w);
    s[0] += f0; q[0] += f0 * f0;
    s[1] += f1; q[1] += f1 * f1;
    s[2] += f2; q[2] += f2 * f2;
    s[3] += f3; q[3] += f3 * f3;
    s[4] += f4; q[4] += f4 * f4;
    s[5] += f5; q[5] += f5 * f5;
    s[6] += f6; q[6] += f6 * f6;
    s[7] += f7; q[7] += f7 * f7;
  }
  __shared__ float lss[256 * 8];
  __shared__ float lqq[256 * 8];
#pragma unroll
  for (int e = 0; e < 8; ++e) {
    lss[threadIdx.x * 8 + e] = s[e];
    lqq[threadIdx.x * 8 + e] = q[e];
  }
  __syncthreads();
  if (threadIdx.x < 128) {
    int f = threadIdx.x;
    int jj = f >> 3, e = f & 7;
    float S = 0.f, Q = 0.f;
#pragma unroll
    for (int gg = 0; gg < 16; ++gg) {
      S += lss[(gg * 16 + jj) * 8 + e];
      Q += lqq[(gg * 16 + jj) * 8 + e];
    }
    unsafeAtomicAdd(bnsum + f, S);
    unsafeAtomicAdd(bnsum + 128 + f, Q);
  }
}

// ---------------------------------------------------------------------------
// gemm2_mfma: scale/shift from bnsum inline; hbn = relu(bn(hb));
// [z | s] = hbn @ [Wn2 | Ws2]; zb bf16, sb = s+b2 bf16. 8 waves/128 rows.
// ---------------------------------------------------------------------------
__global__ __launch_bounds__(512) void gemm2_mfma(
    const unsigned short* __restrict__ hb, const float* __restrict__ bnsum,
    const float* __restrict__ gamma, const float* __restrict__ beta,
    const float* __restrict__ Wn, const float* __restrict__ Ws,
    const float* __restrict__ b, unsigned short* __restrict__ zb,
    unsigned short* __restrict__ sb) {
  __shared__ __align__(16) unsigned short wt[128 * 128];  // [col][k], swizzled
  __shared__ float scs[HID];
  __shared__ float shs[HID];
  __shared__ float bz[OUT_F];
  int tid = threadIdx.x;
  for (int i = tid; i < 128 * 128; i += 512) {
    int k = i >> 7, j = i & 127;
    float v = (j < 64) ? Wn[k * OUT_F + j] : Ws[k * OUT_F + (j - 64)];
    int idx = (j << 7) | k;
    wt[idx ^ ((j & 15) << 3)] = f2bf(v);
  }
  if (tid < HID) {  // bnfinal inline
    const float invn = 1.0f / (float)N_NODES;
    float mu = bnsum[tid] * invn;
    float var = bnsum[128 + tid] * invn - mu * mu;
    float sc = gamma[tid] * rsqrtf(var + BN_EPS);
    scs[tid] = sc;
    shs[tid] = beta[tid] - mu * sc;
  }
  if (tid < OUT_F) bz[tid] = b[tid];
  __syncthreads();

  int wave = tid >> 6, lane = tid & 63;
  int m = lane & 15, kg = lane >> 4;
  int rbase = blockIdx.x * 128 + wave * 16;
  int rowa = rbase + m;
  if (rowa >= N_NODES) rowa = N_NODES - 1;

  short8v a[4];
#pragma unroll
  for (int kt = 0; kt < 4; ++kt) {
    int c0 = kt * 32 + kg * 8;
    uint4 raw = *reinterpret_cast<const uint4*>(hb + (size_t)rowa * HID + c0);
    float4 sc0 = *reinterpret_cast<const float4*>(&scs[c0]);
    float4 sc1 = *reinterpret_cast<const float4*>(&scs[c0 + 4]);
    float4 sh0 = *reinterpret_cast<const float4*>(&shs[c0]);
    float4 sh1 = *reinterpret_cast<const float4*>(&shs[c0 + 4]);
    short8v av;
    av[0] = (short)f2bf(fmaxf(bflo(raw.x) * sc0.x + sh0.x, 0.f));
    av[1] = (short)f2bf(fmaxf(bfhi(raw.x) * sc0.y + sh0.y, 0.f));
    av[2] = (short)f2bf(fmaxf(bflo(raw.y) * sc0.z + sh0.z, 0.f));
    av[3] = (short)f2bf(fmaxf(bfhi(raw.y) * sc0.w + sh0.w, 0.f));
    av[4] = (short)f2bf(fmaxf(bflo(raw.z) * sc1.x + sh1.x, 0.f));
    av[5] = (short)f2bf(fmaxf(bfhi(raw.z) * sc1.y + sh1.y, 0.f));
    av[6] = (short)f2bf(fmaxf(bflo(raw.w) * sc1.z + sh1.z, 0.f));
    av[7] = (short)f2bf(fmaxf(bfhi(raw.w) * sc1.w + sh1.w, 0.f));
    a[kt] = av;
  }

  f32x4 acc[8];
#pragma unroll
  for (int nt = 0; nt < 8; ++nt) acc[nt] = (f32x4){0.f, 0.f, 0.f, 0.f};

#pragma unroll
  for (int nt = 0; nt < 8; ++nt) {
    int col = nt * 16 + m;
    int base = col << 7;
    int sw = (col & 15) << 3;
#pragma unroll
    for (int kt = 0; kt < 4; ++kt) {
      int idx = (base | (kt * 32 + kg * 8)) ^ sw;
      short8v bf = *reinterpret_cast<const short8v*>(&wt[idx]);
      acc[nt] = __builtin_amdgcn_mfma_f32_16x16x32_bf16(a[kt], bf, acc[nt], 0, 0, 0);
    }
  }

#pragma unroll
  for (int nt = 0; nt < 8; ++nt) {
    int col = nt * 16 + m;
#pragma unroll
    for (int r = 0; r < 4; ++r) {
      int rr = rbase + kg * 4 + r;
      if (rr < N_NODES) {
        float v = acc[nt][r];
        if (col < 64)
          zb[(size_t)rr * OUT_F + col] = f2bf(v);
        else
          sb[(size_t)rr * OUT_F + (col - 64)] = f2bf(v + bz[col - 64]);
      }
    }
  }
}

// ---------------------------------------------------------------------------
extern "C" void kernel_launch(void* const* d_in, const int* in_sizes, int n_in,
                              void* d_out, int out_size, void* d_ws,
                              size_t ws_size, hipStream_t stream) {
  const float* x = (const float*)d_in[0];
  const int* esrc = (const int*)d_in[1];
  const int* edst = (const int*)d_in[2];
  const float* Ws1 = (const float*)d_in[3];
  const float* Wn1 = (const float*)d_in[4];
  const float* b1 = (const float*)d_in[5];
  const float* gamma = (const float*)d_in[6];
  const float* beta = (const float*)d_in[7];
  const float* Ws2 = (const float*)d_in[8];
  const float* Wn2 = (const float*)d_in[9];
  const float* b2 = (const float*)d_in[10];
  float* out = (float*)d_out;

  float* ws = (float*)d_ws;
  float* bnsum = ws;                         // 256
  int* cursor = (int*)(ws + 512);            // N (degrees after pass1)
  int* rowstart = cursor + N_NODES;          // N+1
  int* bsum = rowstart + N_NODES + 1;        // SCAN_NBLK
  int* boff = bsum + SCAN_NBLK;              // SCAN_NBLK
  int* csr = boff + SCAN_NBLK;               // E
  int pos16_off = ((512 + 2 * N_NODES + 1 + 2 * SCAN_NBLK + N_EDGES) + 3) & ~3;
  unsigned short* pos16 = (unsigned short*)(ws + pos16_off);        // E ushort
  unsigned short* xb = (unsigned short*)(ws + pos16_off + N_EDGES / 2);
  unsigned short* zbuf = xb + (size_t)N_NODES * 64;                 // N*64
  unsigned short* sb = zbuf + (size_t)N_NODES * 64;                 // N*64
  unsigned short* hb = sb + (size_t)N_NODES * 64;                   // N*128

  const int e4grid = (N_EDGES / 4 + 255) / 256;
  cvtzero_kernel<<<(N_NODES * IN_F / 8 + 255) / 256, 256, 0, stream>>>(x, xb,
                                                                       cursor);
  pass1_kernel<<<e4grid, 256, 0, stream>>>(edst, cursor, pos16);
  blocksum_kernel<<<SCAN_NBLK, 256, 0, stream>>>(cursor, bsum);
  scanb_kernel<<<1, 512, 0, stream>>>(bsum, boff, rowstart, bnsum);
  writerow_kernel<<<SCAN_NBLK, 256, 0, stream>>>(cursor, boff, rowstart);
  scatter_kernel<<<e4grid, 256, 0, stream>>>(esrc, edst, pos16, rowstart, csr);

  const int ggrid = (N_NODES + 127) / 128;
  const int agrid = (N_NODES + 31) / 32;
  // layer 1 (fused): hb = [xb | mean_in(xb)] @ [Ws1;Wn1] + b1
  gemm1_fused<<<ggrid, 512, 0, stream>>>(xb, rowstart, csr, Ws1, Wn1, b1, hb);

  // batchnorm stats (finalize folded into gemm2 prologue)
  bnstats_kernel<<<256, 256, 0, stream>>>(hb, bnsum);

  // layer 2: [zb|sb] = relu(bn(hb)) @ [Wn2|Ws2]; out = sb + mean_in(zb)
  gemm2_mfma<<<ggrid, 512, 0, stream>>>(hb, bnsum, gamma, beta, Wn2, Ws2, b2,
                                        zbuf, sb);
  aggb2_kernel<<<agrid, 256, 0, stream>>>(zbuf, sb, rowstart, csr, out);
}